// Round 5
// baseline (409.691 us; speedup 1.0000x reference)
//
#include <hip/hip_runtime.h>
#include <math.h>

#define NN      262144
#define WC      128
#define RR      4
#define OUTD    512
#define IFACED  919
#define CD      1431
#define C4      5724
#define VROWS   1559   // CD + WC virtual rows ([h ; xt])
#define ZCH     45     // virtual-row chunks of ZROW (45*35=1575 >= 1559)
#define ZROW    35     // 45*5724=257580 tasks <= 262144 threads (no 2-task tail)
#define PROJ_J  1157   // 512 out + 645 used iface entries
#define CMAX    2048   // candidate cap (E[n]=524 @ thr 2e-3)
#define PKT     48     // proj k-chunks of 30

// ---- ws word offsets. [0 .. WS_ZERO_WORDS) zeroed by k_init pre-launch.
#define OFF_SLOT    0                    // u32[512] per-block arrival slots (16 lines, stores only)
#define OFF_REL     512                  // u32 release epoch (own 128B line)
#define OFF_CCNT    544                  // u32 candidate count (own line)
#define OFF_Z       576                  // f32[5][C4] -> end 29196
#define OFF_IFC     29196                // f32[919] iface accumulator
#define OFF_PO      30116                // f32[512] out-proj accumulator
#define WS_ZERO_WORDS 30628
#define OFF_BSUM    30656                // f32[512*5] per-block softmax sums
#define OFF_CAND    33280                // u64[2048] (8B aligned)
#define OFF_SCORES  37440                // f32[5*NN] (agent store/load, cross-block)

__device__ __forceinline__ float sigm(float x) { return 1.f / (1.f + expf(-x)); }
__device__ __forceinline__ float softplusf(float x) { return x > 20.f ? x : log1pf(expf(x)); }

// agent-scope (device-coherent) accessors — land at the coherent point,
// bypass stale per-XCD L2s. No L2 writeback/invalidate anywhere.
__device__ __forceinline__ float gldf(const float* p) {
  return __hip_atomic_load(p, __ATOMIC_RELAXED, __HIP_MEMORY_SCOPE_AGENT);
}
__device__ __forceinline__ void gstf(float* p, float v) {
  __hip_atomic_store(p, v, __ATOMIC_RELAXED, __HIP_MEMORY_SCOPE_AGENT);
}
__device__ __forceinline__ unsigned gldu(const unsigned* p) {
  return __hip_atomic_load(p, __ATOMIC_RELAXED, __HIP_MEMORY_SCOPE_AGENT);
}
__device__ __forceinline__ unsigned long long gldu64(const unsigned long long* p) {
  return __hip_atomic_load(p, __ATOMIC_RELAXED, __HIP_MEMORY_SCOPE_AGENT);
}
__device__ __forceinline__ void gstu64(unsigned long long* p, unsigned long long v) {
  __hip_atomic_store(p, v, __ATOMIC_RELAXED, __HIP_MEMORY_SCOPE_AGENT);
}

// ---- init: zero slots/rel/ccnt/z/ifc/po (plain launch, capture-safe) ------
__global__ void k_init(float* __restrict__ ws) {
  int t = blockIdx.x * 1024 + threadIdx.x;
  if (t < WS_ZERO_WORDS) ws[t] = 0.f;
}

// ---- grid barrier v4: ZERO arrival RMWs.
// Each block STORES its epoch to its own slot word (plain agent store —
// no exclusive-ownership round trip; v3's striped fetch_add serialized
// ~64 RMW/line ≈ 6.4us). Block 0 polls all slots with 512 threads in
// parallel (reads only), then publishes the epoch to a separate release
// line; other blocks poll release read-only at low rate.
__device__ __forceinline__ void gbar(unsigned* slots, unsigned* rel, unsigned ep) {
  asm volatile("s_waitcnt vmcnt(0) lgkmcnt(0)" ::: "memory");  // drain stores/atomics
  __syncthreads();                                             // whole block drained
  if (blockIdx.x == 0) {
    unsigned t = threadIdx.x;
    if (t > 0 && t < gridDim.x) {
      while (__hip_atomic_load(slots + t, __ATOMIC_RELAXED, __HIP_MEMORY_SCOPE_AGENT) < ep)
        __builtin_amdgcn_s_sleep(4);
    }
    __syncthreads();
    if (t == 0)
      __hip_atomic_store(rel, ep, __ATOMIC_RELAXED, __HIP_MEMORY_SCOPE_AGENT);
  } else {
    if (threadIdx.x == 0) {
      __hip_atomic_store(slots + blockIdx.x, ep, __ATOMIC_RELAXED, __HIP_MEMORY_SCOPE_AGENT);
      while (__hip_atomic_load(rel, __ATOMIC_RELAXED, __HIP_MEMORY_SCOPE_AGENT) < ep)
        __builtin_amdgcn_s_sleep(8);
    }
  }
  __syncthreads();
}

__global__ __launch_bounds__(512, 4) void k_fused(
    const float* __restrict__ x,  const float* __restrict__ dk,
    const float* __restrict__ db, const float* __restrict__ lk,
    const float* __restrict__ lr, const float* __restrict__ lb,
    const float* __restrict__ h0, const float* __restrict__ c0,
    const float* __restrict__ rv, const float* __restrict__ Wo,
    const float* __restrict__ Wi, const float* __restrict__ M,
    const float* __restrict__ us, float* __restrict__ out,
    float* __restrict__ ws)
{
  const unsigned T   = gridDim.x * blockDim.x;
  const unsigned tid = blockIdx.x * blockDim.x + threadIdx.x;
  unsigned* slots = (unsigned*)(ws + OFF_SLOT);
  unsigned* rel   = (unsigned*)(ws + OFF_REL);
  unsigned* ccnt  = (unsigned*)(ws + OFF_CCNT);
  float* ifc      = ws + OFF_IFC;
  float* po       = ws + OFF_PO;
  float* bsum     = ws + OFF_BSUM;
  float* scores   = ws + OFF_SCORES;
  unsigned long long* cand = (unsigned long long*)(ws + OFF_CAND);
  unsigned ep = 0;

  __shared__ float sv[VROWS];       // [h(1431) ; xt(128)] per-block replica
  __shared__ float scc[CD];         // c, per-block replica
  __shared__ float sxw[512];        // dense partials; [0:128) holds xw after
  __shared__ float s_rk[RR * WC];
  __shared__ float s_wk[WC];
  __shared__ float swred[8][5];
  __shared__ float ssum[5];
  __shared__ unsigned long long sc[CMAX];
  __shared__ unsigned long long srt[CMAX];
  __shared__ float cpe[200];

  // ---- init: h0/c0 -> LDS; xw = x@dense+bias computed redundantly per block
  for (int t = threadIdx.x; t < CD; t += 512) { sv[t] = h0[t]; scc[t] = c0[t]; }
  {
    int j = threadIdx.x & (WC - 1), kc = threadIdx.x >> 7;   // 4 k-chunks x 128
    const float* col = dk + j;
    float a = 0.f;
    int k0 = kc * 128;
    #pragma unroll 8
    for (int k = k0; k < k0 + 128; ++k) a = fmaf(x[k], col[(size_t)k * WC], a);
    sxw[threadIdx.x] = a;
  }
  __syncthreads();
  {
    float v = 0.f;
    if (threadIdx.x < WC)
      v = db[threadIdx.x] + sxw[threadIdx.x] + sxw[threadIdx.x + 128] +
          sxw[threadIdx.x + 256] + sxw[threadIdx.x + 384];
    __syncthreads();
    if (threadIdx.x < WC) sxw[threadIdx.x] = v;
    __syncthreads();
  }

  // ---- LSTM: 5 steps. One barrier per step; gates redundant per block. -----
  // z_s pre-zeroed by k_init; bias folded into gates. Balanced split-K over
  // the virtual [h;xt] vector: 45 chunks x 35 rows -> <=1 task per thread.
  for (int step = 0; step < 5; ++step) {
    if (threadIdx.x < WC)
      sv[CD + threadIdx.x] = (step == 0) ? sxw[threadIdx.x]
                                         : rv[(step - 1) * WC + threadIdx.x];
    __syncthreads();
    float* zs = ws + OFF_Z + step * C4;
    for (unsigned task = tid; task < (unsigned)(ZCH * C4); task += T) {
      int ch = (int)(task / (unsigned)C4);
      int j  = (int)(task - (unsigned)ch * C4);
      int kv0 = ch * ZROW, kv1 = kv0 + ZROW; if (kv1 > VROWS) kv1 = VROWS;
      float acc = 0.f;
      int kb = kv1 < CD ? kv1 : CD;
      const float* col = lr + j;
      #pragma unroll 5
      for (int k = kv0; k < kb; ++k) acc = fmaf(sv[k], col[(size_t)k * C4], acc);
      if (kv1 > CD) {
        const float* colk = lk + j;
        int ka = kv0 > CD ? kv0 : CD;
        for (int k = ka; k < kv1; ++k) acc = fmaf(sv[k], colk[(size_t)(k - CD) * C4], acc);
      }
      atomicAdd(&zs[j], acc);   // device-scope: lands at coherent point
    }
    ++ep; gbar(slots, rel, ep);
    // gates: every block redundantly, z via agent loads, h/c stay in LDS
    for (int j = threadIdx.x; j < CD; j += 512) {
      float zi = gldf(zs + j)          + lb[j];
      float zf = gldf(zs + CD + j)     + lb[CD + j];
      float zg = gldf(zs + 2 * CD + j) + lb[2 * CD + j];
      float zo = gldf(zs + 3 * CD + j) + lb[3 * CD + j];
      float cn = sigm(zf) * scc[j] + sigm(zi) * tanhf(zg);
      scc[j] = cn;
      sv[j]  = sigm(zo) * tanhf(cn);
    }
    __syncthreads();
  }

  // ---- projection: split-K, atomicAdd into po (out) / ifc ------------------
  for (unsigned task = tid; task < (unsigned)(PKT * PROJ_J); task += T) {
    int kt = (int)(task / (unsigned)PROJ_J);
    int j  = (int)(task - (unsigned)kt * PROJ_J);
    const float* col; int stride; float* dst;
    if (j < OUTD) { col = Wo + j; stride = OUTD; dst = po + j; }
    else { col = Wi + (j - OUTD); stride = IFACED; dst = ifc + (j - OUTD); }
    int k0 = kt * 30, k1 = k0 + 30; if (k1 > CD) k1 = CD;
    float acc = 0.f;
    #pragma unroll 6
    for (int k = k0; k < k1; ++k) acc = fmaf(sv[k], col[(size_t)k * stride], acc);
    atomicAdd(dst, acc);
  }
  ++ep; gbar(slots, rel, ep);

  // ---- block 0 copies po -> out[0:512]; all blocks normalize keys ----------
  if (blockIdx.x == 0) out[threadIdx.x] = gldf(po + threadIdx.x);
  if (threadIdx.x < 320) {
    int w = threadIdx.x >> 6, lane = threadIdx.x & 63;
    float beta = 1.f + softplusf((w < 4) ? gldf(ifc + RR * WC + w)
                                         : gldf(ifc + RR * WC + RR + WC));
    const float* src = (w < 4) ? (ifc + w * WC) : (ifc + RR * WC + RR);
    float v0 = gldf(src + lane), v1 = gldf(src + lane + 64);
    float sq = v0 * v0 + v1 * v1;
    for (int off = 1; off < 64; off <<= 1) sq += __shfl_xor(sq, off);
    float rn = rsqrtf(fmaxf(sq, 1e-12f)) * beta;
    float* dstp = (w < 4) ? (s_rk + w * WC) : s_wk;
    dstp[lane] = v0 * rn; dstp[lane + 64] = v1 * rn;
  }
  __syncthreads();

  // ---- scores: one row per thread, keys from LDS; also alloc zero-fill +
  //      candidate filter (us-only dependencies) fused into this HBM phase ---
  float p0 = 0, p1 = 0, p2 = 0, p3 = 0, p4 = 0;
  {
    const float4* K0 = (const float4*)(s_rk);
    const float4* K1 = (const float4*)(s_rk + WC);
    const float4* K2 = (const float4*)(s_rk + 2 * WC);
    const float4* K3 = (const float4*)(s_rk + 3 * WC);
    const float4* KW = (const float4*)(s_wk);
    for (unsigned i = tid; i < NN; i += T) {
      const float4* rowp = (const float4*)(M + (size_t)i * WC);
      float a0 = 0, a1 = 0, a2 = 0, a3 = 0, a4 = 0, sq = 0;
      #pragma unroll 4
      for (int k = 0; k < 32; ++k) {
        float4 m = rowp[k];
        float4 c0v = K0[k], c1v = K1[k], c2v = K2[k], c3v = K3[k], cwv = KW[k];
        sq = fmaf(m.x, m.x, fmaf(m.y, m.y, fmaf(m.z, m.z, fmaf(m.w, m.w, sq))));
        a0 = fmaf(m.x, c0v.x, fmaf(m.y, c0v.y, fmaf(m.z, c0v.z, fmaf(m.w, c0v.w, a0))));
        a1 = fmaf(m.x, c1v.x, fmaf(m.y, c1v.y, fmaf(m.z, c1v.z, fmaf(m.w, c1v.w, a1))));
        a2 = fmaf(m.x, c2v.x, fmaf(m.y, c2v.y, fmaf(m.z, c2v.z, fmaf(m.w, c2v.w, a2))));
        a3 = fmaf(m.x, c3v.x, fmaf(m.y, c3v.y, fmaf(m.z, c3v.z, fmaf(m.w, c3v.w, a3))));
        a4 = fmaf(m.x, cwv.x, fmaf(m.y, cwv.y, fmaf(m.z, cwv.z, fmaf(m.w, cwv.w, a4))));
      }
      float rn = rsqrtf(fmaxf(sq, 1e-12f));
      float e0 = expf(a0 * rn), e1 = expf(a1 * rn), e2 = expf(a2 * rn),
            e3 = expf(a3 * rn), e4 = expf(a4 * rn);
      // agent stores: re-read by OTHER blocks after the barrier
      gstf(scores + 0 * (size_t)NN + i, e0);
      gstf(scores + 1 * (size_t)NN + i, e1);
      gstf(scores + 2 * (size_t)NN + i, e2);
      gstf(scores + 3 * (size_t)NN + i, e3);
      gstf(scores + 4 * (size_t)NN + i, e4);
      gstf(out + OUTD + 5 * (size_t)NN + i, 0.f);  // alloc col zero-fill
      float u = us[i];
      if (u < 2e-3f) {
        unsigned slot = atomicAdd(ccnt, 1u);
        if (slot < CMAX)
          gstu64(cand + slot, ((unsigned long long)__float_as_uint(u) << 32) | i);
      }
      p0 += e0; p1 += e1; p2 += e2; p3 += e3; p4 += e4;
    }
  }
  {
    for (int off = 1; off < 64; off <<= 1) {
      p0 += __shfl_xor(p0, off); p1 += __shfl_xor(p1, off); p2 += __shfl_xor(p2, off);
      p3 += __shfl_xor(p3, off); p4 += __shfl_xor(p4, off);
    }
    int wv = threadIdx.x >> 6, ln = threadIdx.x & 63;
    if (ln == 0) { swred[wv][0] = p0; swred[wv][1] = p1; swred[wv][2] = p2;
                   swred[wv][3] = p3; swred[wv][4] = p4; }
    __syncthreads();
    if (threadIdx.x < 5) {
      float s = 0.f;
      for (int q = 0; q < 8; ++q) s += swred[q][threadIdx.x];
      gstf(bsum + blockIdx.x * 5 + threadIdx.x, s);
    }
  }
  ++ep; gbar(slots, rel, ep);

  // ---- FINAL (no more barriers): block 0 -> alloc; blocks 1.. -> normalize -
  if (blockIdx.x == 0) {
    // alloc: exact rank-sort of candidates + fp32 cumprod (reference order).
    // cumprod of sorted ascending uniforms underflows after ~10 terms; ranks
    // >=200 keep the zero written in the scores phase (ref there < 1e-38).
    int n = (int)gldu(ccnt); if (n > CMAX) n = CMAX;
    for (int t = threadIdx.x; t < n; t += 512) sc[t] = gldu64(cand + t);
    __syncthreads();
    for (int t = threadIdx.x; t < n; t += 512) {
      unsigned long long v = sc[t];
      int r = 0;
      for (int j2 = 0; j2 < n; ++j2) r += (sc[j2] < v);
      srt[r] = v;
    }
    __syncthreads();
    int lim = n < 200 ? n : 200;
    if (threadIdx.x == 0) {
      float cp = 1.f;
      for (int r = 0; r < lim; ++r) {
        cpe[r] = cp;
        cp *= __uint_as_float((unsigned)(srt[r] >> 32));
      }
    }
    __syncthreads();
    for (int r = threadIdx.x; r < lim; r += 512) {
      unsigned long long pr = srt[r];
      float s = __uint_as_float((unsigned)(pr >> 32));
      gstf(out + OUTD + 5 * (size_t)NN + (unsigned)pr, (1.f - s) * cpe[r]);
    }
  } else {
    // totals (redundant per block)
    float q0 = 0, q1 = 0, q2 = 0, q3 = 0, q4 = 0;
    for (unsigned t = threadIdx.x; t < gridDim.x; t += 512) {
      const float* bp = bsum + t * 5;
      q0 += gldf(bp); q1 += gldf(bp + 1); q2 += gldf(bp + 2);
      q3 += gldf(bp + 3); q4 += gldf(bp + 4);
    }
    for (int off = 1; off < 64; off <<= 1) {
      q0 += __shfl_xor(q0, off); q1 += __shfl_xor(q1, off); q2 += __shfl_xor(q2, off);
      q3 += __shfl_xor(q3, off); q4 += __shfl_xor(q4, off);
    }
    int wv = threadIdx.x >> 6, ln = threadIdx.x & 63;
    if (ln == 0) { swred[wv][0] = q0; swred[wv][1] = q1; swred[wv][2] = q2;
                   swred[wv][3] = q3; swred[wv][4] = q4; }
    __syncthreads();
    if (threadIdx.x < 5) {
      float s = 0.f;
      for (int q = 0; q < 8; ++q) s += swred[q][threadIdx.x];
      ssum[threadIdx.x] = s;
    }
    __syncthreads();
    float i0 = 1.f / ssum[0], i1 = 1.f / ssum[1], i2 = 1.f / ssum[2],
          i3 = 1.f / ssum[3], i4 = 1.f / ssum[4];
    // shifted mapping excludes block 0 (busy with alloc)
    unsigned stride = (gridDim.x - 1) * 512;
    for (unsigned i = (blockIdx.x - 1) * 512 + threadIdx.x; i < NN; i += stride) {
      float4 wr;
      wr.x = gldf(scores + 0 * (size_t)NN + i) * i0;
      wr.y = gldf(scores + 1 * (size_t)NN + i) * i1;
      wr.z = gldf(scores + 2 * (size_t)NN + i) * i2;
      wr.w = gldf(scores + 3 * (size_t)NN + i) * i3;
      *(float4*)(out + OUTD + (size_t)i * 4) = wr;   // single writer
      out[OUTD + 4 * (size_t)NN + i] = gldf(scores + 4 * (size_t)NN + i) * i4;
    }
  }
}

extern "C" void kernel_launch(void* const* d_in, const int* in_sizes, int n_in,
                              void* d_out, int out_size, void* d_ws, size_t ws_size,
                              hipStream_t stream) {
  const float* x  = (const float*)d_in[0];
  const float* dk = (const float*)d_in[1];
  const float* db = (const float*)d_in[2];
  const float* lk = (const float*)d_in[3];
  const float* lr = (const float*)d_in[4];
  const float* lb = (const float*)d_in[5];
  const float* h0 = (const float*)d_in[6];
  const float* c0 = (const float*)d_in[7];
  const float* rv = (const float*)d_in[8];
  const float* Wo = (const float*)d_in[9];
  const float* Wi = (const float*)d_in[10];
  const float* M  = (const float*)d_in[11];
  const float* us = (const float*)d_in[12];
  float* out = (float*)d_out;
  float* ws  = (float*)d_ws;

  static int grid = 0;
  if (grid == 0) {
    int nb = 0;
    if (hipOccupancyMaxActiveBlocksPerMultiprocessor(&nb, (const void*)k_fused, 512, 0) != hipSuccess || nb < 1)
      nb = 1;
    long g = (long)nb * 256;        // 256 CUs; always >= 256 blocks
    grid = (int)(g < 512 ? g : 512);
  }

  // zero slots/rel/ccnt/z[5]/ifc/po — plain kernel, capture-safe
  k_init<<<(WS_ZERO_WORDS + 1023) / 1024, 1024, 0, stream>>>(ws);

  void* args[] = { &x, &dk, &db, &lk, &lr, &lb, &h0, &c0, &rv,
                   &Wo, &Wi, &M, &us, &out, &ws };
  hipLaunchCooperativeKernel((const void*)k_fused, dim3(grid), dim3(512),
                             args, 0, stream);
}